// Round 3
// baseline (28.405 us; speedup 1.0000x reference)
//
#include <hip/hip_runtime.h>

// pred (B,C,S) f32, labels (B,S) int32, scalar f32 out.
constexpr int   Bn    = 512;
constexpr int   Cn    = 4;
constexpr int   Sn    = 16384;
constexpr int   PADv  = 3;
constexpr float Qv    = 0.7f;
constexpr int   BPB   = 8;            // blocks per batch
constexpr int   CHUNK = Sn / BPB;     // 2048 positions per block (2 sub-iters of 1024)

// ws layout: float psum[Bn*BPB]; int pcnt[Bn*BPB]; float lastg[Bn]
// Every slot written unconditionally each call -> no init, no atomics,
// deterministic reduction order.

__device__ __forceinline__ float gce_raw(float l0, float l1, float l2, int lb)
{
    const float m   = fmaxf(fmaxf(l0, l1), l2);
    const float e0  = __expf(l0 - m);
    const float e1  = __expf(l1 - m);
    const float e2  = __expf(l2 - m);
    const float inv = 1.0f / (e0 + e1 + e2);
    const int   c   = min(max(lb, 0), 2);          // safe_lab
    float pt = ((c == 0) ? e0 : (c == 1) ? e1 : e2) * inv;
    pt = fminf(fmaxf(pt, 1e-7f), 1.0f);            // clip(probs)
    return 1.0f - __expf(Qv * __logf(pt));         // 1 - pt^Q  (pt >= 1e-7 > 0)
}

// ---------------------------------------------------------------------------
// Main pass. mask = (label != PAD); PAD is a contiguous suffix, so the mask
// equals s < j and count(non-pad) = j. Lower-half blocks (s < S/2, lengths
// >= S/2) issue ALL loads up front in one memory epoch; upper-half blocks
// gate pred loads on a wave-uniform "not all pad" test, with both label
// vectors loaded first so only one dependent wait occurs.
// ---------------------------------------------------------------------------
__global__ __launch_bounds__(256) void gce_main(
    const float* __restrict__ pred, const int* __restrict__ labels,
    float* __restrict__ psum, int* __restrict__ pcnt, float* __restrict__ lastg)
{
    const int b   = blockIdx.x >> 3;          // / BPB
    const int blk = blockIdx.x & (BPB - 1);
    const int t   = threadIdx.x;
    const int s0  = blk * CHUNK;

    const float4* p0  = reinterpret_cast<const float4*>(pred + ((size_t)b * Cn + 0) * Sn);
    const float4* p1  = reinterpret_cast<const float4*>(pred + ((size_t)b * Cn + 1) * Sn);
    const float4* p2  = reinterpret_cast<const float4*>(pred + ((size_t)b * Cn + 2) * Sn);
    const int4*   lab = reinterpret_cast<const int4*>(labels + (size_t)b * Sn);

    const int vi0 = (s0 >> 2) + t;            // sub-iter 0: positions s0 + 4t
    const int vi1 = vi0 + 256;                // sub-iter 1: positions s0 + 1024 + 4t

    float acc = 0.0f;
    int   cnt = 0;
    float gl  = 0.0f;   // unmasked gce at global last position (no-pad fallback)

    auto proc4 = [&](const int4& lv, const float4& x0, const float4& x1,
                     const float4& x2) -> float {
        const float g0 = gce_raw(x0.x, x1.x, x2.x, lv.x);
        const float g1 = gce_raw(x0.y, x1.y, x2.y, lv.y);
        const float g2 = gce_raw(x0.z, x1.z, x2.z, lv.z);
        const float g3 = gce_raw(x0.w, x1.w, x2.w, lv.w);
        if (lv.x != PADv) { acc += g0; ++cnt; }
        if (lv.y != PADv) { acc += g1; ++cnt; }
        if (lv.z != PADv) { acc += g2; ++cnt; }
        if (lv.w != PADv) { acc += g3; ++cnt; }
        return g3;
    };

    if (blk < BPB / 2) {
        // s < S/2: never pad (lengths >= S/2). One memory epoch: 8 loads in flight.
        const int4   lv0 = lab[vi0];
        const int4   lv1 = lab[vi1];
        const float4 a0 = p0[vi0], u0 = p1[vi0], v0 = p2[vi0];
        const float4 a1 = p0[vi1], u1 = p1[vi1], v1 = p2[vi1];
        proc4(lv0, a0, u0, v0);
        proc4(lv1, a1, u1, v1);
    } else {
        const int4 lv0 = lab[vi0];
        const int4 lv1 = lab[vi1];
        const bool ap0 = (lv0.x == PADv) & (lv0.y == PADv) &
                         (lv0.z == PADv) & (lv0.w == PADv);
        const bool ap1 = (lv1.x == PADv) & (lv1.y == PADv) &
                         (lv1.z == PADv) & (lv1.w == PADv);
        const bool go0 = !__all(ap0);
        const bool go1 = !__all(ap1);
        float4 a0, u0, v0, a1, u1, v1;
        if (go0) { a0 = p0[vi0]; u0 = p1[vi0]; v0 = p2[vi0]; }   // issue loads for
        if (go1) { a1 = p0[vi1]; u1 = p1[vi1]; v1 = p2[vi1]; }   // BOTH iters first
        if (go0) { proc4(lv0, a0, u0, v0); }
        if (go1) {
            const float g3 = proc4(lv1, a1, u1, v1);
            if (blk == BPB - 1 && t == 255) gl = g3;  // s = Sn-1 owner
        }
    }

    // block-wide reduce: 64-lane shuffle, then across 4 waves via LDS
    #pragma unroll
    for (int off = 32; off > 0; off >>= 1) {
        acc += __shfl_down(acc, off, 64);
        cnt += __shfl_down(cnt, off, 64);
    }
    __shared__ float wsum[4];
    __shared__ int   wcnt[4];
    if ((t & 63) == 0) { wsum[t >> 6] = acc; wcnt[t >> 6] = cnt; }
    __syncthreads();
    if (t == 0) {
        psum[blockIdx.x] = wsum[0] + wsum[1] + wsum[2] + wsum[3];
        pcnt[blockIdx.x] = wcnt[0] + wcnt[1] + wcnt[2] + wcnt[3];
    }
    if (blk == BPB - 1 && t == 255) lastg[b] = gl;
}

// ---------------------------------------------------------------------------
// Finisher: one block combines the 4096 partials -> scalar mean.
// ---------------------------------------------------------------------------
__global__ __launch_bounds__(256) void gce_final(
    const float* __restrict__ psum, const int* __restrict__ pcnt,
    const float* __restrict__ lastg, float* __restrict__ out)
{
    const int t = threadIdx.x;
    float acc = 0.0f;
    for (int b = t; b < Bn; b += 256) {
        float s = 0.0f; int c = 0;
        #pragma unroll
        for (int k = 0; k < BPB; ++k) {
            s += psum[b * BPB + k];
            c += pcnt[b * BPB + k];
        }
        float jf;
        if (c == Sn) { s -= lastg[b]; jf = (float)(Sn - 1); }  // no-pad corner
        else         { jf = (float)c; }
        acc += s / (Qv * jf);
    }
    #pragma unroll
    for (int off = 32; off > 0; off >>= 1) acc += __shfl_down(acc, off, 64);
    __shared__ float w[4];
    if ((t & 63) == 0) w[t >> 6] = acc;
    __syncthreads();
    if (t == 0) out[0] = (w[0] + w[1] + w[2] + w[3]) / (float)Bn;
}

// ---------------------------------------------------------------------------
extern "C" void kernel_launch(void* const* d_in, const int* in_sizes, int n_in,
                              void* d_out, int out_size, void* d_ws, size_t ws_size,
                              hipStream_t stream)
{
    const float* pred   = (const float*)d_in[0];
    const int*   labels = (const int*)d_in[1];
    float*       out    = (float*)d_out;

    float* psum  = (float*)d_ws;                 // 4096 f32
    int*   pcnt  = (int*)(psum + Bn * BPB);      // 4096 i32
    float* lastg = (float*)(pcnt + Bn * BPB);    // 512 f32

    hipLaunchKernelGGL(gce_main, dim3(Bn * BPB), dim3(256), 0, stream,
                       pred, labels, psum, pcnt, lastg);
    hipLaunchKernelGGL(gce_final, dim3(1), dim3(256), 0, stream,
                       psum, pcnt, lastg, out);
}